// Round 5
// baseline (28.345 us; speedup 1.0000x reference)
//
#include <hip/hip_runtime.h>

// CubPL2d: persistence landscape top-2 over pairs.
// x: [B=128, C=64, H=64, W=64] f32; birth/death/pair_dim: [B, C, P=128] i32.
// out: [B, C, D=2, K=2, T=32] f32.
//
// R4: convert the random x-gather (measured ~5.0 TB/s effective) into a
// coalesced full-slice stream (fills measure ~7 TB/s on this chip):
//   - each wave reg-stages its 16 KB slice (16x global_load_dwordx4,
//     coalesced) -> 16x ds_write_b128 into a wave-private LDS buffer,
//   - gathers its 4 values with per-lane ds_read (random addr, cheap),
//   - then OVERLAYS the compacted per-dim tables onto the dead slice buffer
//     (in-order same-wave DS pipe + lgkmcnt fences make this safe).
// Traffic grows 116->134 MB on x but runs at streaming rate. One wave per
// slice (R2 structure: R3 showed 2-slice ILP-for-TLP trade regresses).
// LDS = 4 x 16 KB = 64 KB/block -> 2 blocks/CU, 8 waves/CU; 16 outstanding
// dwordx4 per wave = 128 KB in flight per CU >> BW*latency (~10 KB).

constexpr int P = 128;
constexpr float T_MIN = 0.03f;
constexpr float T_MAX = 0.34f;
constexpr float BIG = 1e30f;

__global__ __launch_bounds__(256) void pl_topk_kernel(
    const float* __restrict__ x,
    const int* __restrict__ birth_idx,
    const int* __restrict__ death_idx,
    const int* __restrict__ pair_dim,
    float* __restrict__ out)
{
    // one 4096-float slice buffer per wave; tables overlay first 2080 B later
    __shared__ float slice[4][4096];

    const int lane = threadIdx.x & 63;
    const int w = threadIdx.x >> 6;
    const int wid = blockIdx.x * 4 + w;   // wid = b*C + c, 0..8191

    const int d_lane = lane >> 5;    // homology dim this lane accumulates
    const int t_idx = lane & 31;     // time step this lane accumulates
    const float t = T_MIN + (T_MAX - T_MIN) * (float)t_idx * (1.0f / 31.0f);

    // ---- issue idx loads (coalesced int2; lane owns pairs 2l, 2l+1) ----
    const long pbase = (long)wid * P;
    const int2 bi = *reinterpret_cast<const int2*>(&birth_idx[pbase + 2 * lane]);
    const int2 di = *reinterpret_cast<const int2*>(&death_idx[pbase + 2 * lane]);
    const int2 dm = *reinterpret_cast<const int2*>(&pair_dim[pbase + 2 * lane]);

    // ---- stream the whole 16 KB x-slice, coalesced (16 x dwordx4) ----
    const float4* xs = reinterpret_cast<const float4*>(x + (long)wid * 4096);
    float4 s[16];
    #pragma unroll
    for (int c = 0; c < 16; ++c) s[c] = xs[c * 64 + lane];

    // ---- compaction positions via ballot popcount prefix (overlaps loads) ----
    const unsigned long long below = (1ull << lane) - 1ull;
    const unsigned long long a1 = __ballot(dm.x == 1);   // elem A (pair 2l)
    const unsigned long long b1 = __ballot(dm.y == 1);   // elem B (pair 2l+1)
    const int nA0 = __popcll(~a1);               // dim-0 count among A elems
    const int nA1 = 64 - nA0;
    const int n0 = nA0 + __popcll(~b1);          // total dim-0 pairs
    const int n1 = P - n0;
    const int posA = __popcll((dm.x ? a1 : ~a1) & below);
    const int posB = (dm.y ? nA1 : nA0) + __popcll((dm.y ? b1 : ~b1) & below);

    // ---- write slice to this wave's LDS buffer (16 x ds_write_b128) ----
    float* sl = slice[w];
    #pragma unroll
    for (int c = 0; c < 16; ++c)
        *reinterpret_cast<float4*>(&sl[(c * 64 + lane) * 4]) = s[c];

    asm volatile("s_waitcnt lgkmcnt(0)" ::: "memory");

    // ---- gather this lane's 4 values from LDS (random addr, per-lane) ----
    const float xb0 = sl[bi.x];
    const float xb1 = sl[bi.y];
    const float xd0 = sl[di.x];
    const float xd1 = sl[di.y];

    // all gathers (reads) complete before the table overlay (writes)
    asm volatile("s_waitcnt lgkmcnt(0)" ::: "memory");

    // ---- build compacted dim tables overlaid on the dead slice buffer ----
    // entry (d, i) at tab[d*130 + i]; 130*8 = 1040 B keeps dim 1 16B-aligned.
    float2* tab = reinterpret_cast<float2*>(sl);
    tab[dm.x * 130 + posA] = make_float2(xb0, xd0);
    tab[dm.y * 130 + posB] = make_float2(xb1, xd1);
    if (lane == 0) tab[n0] = make_float2(BIG, -BIG);        // odd-tail sentinels
    if (lane == 1) tab[130 + n1] = make_float2(BIG, -BIG);

    asm volatile("s_waitcnt lgkmcnt(0)" ::: "memory");

    // ---- top-2 scan over my dim's compacted list (b128 broadcast reads) ----
    const int n_mine = d_lane ? n1 : n0;
    float m1 = 0.0f, m2 = 0.0f;
    const float2* tp = &tab[d_lane * 130];
    #pragma unroll 2
    for (int p = 0; p < n_mine; p += 2) {
        const float4 e = *reinterpret_cast<const float4*>(&tp[p]);
        const float v0 = fminf(t - e.x, e.y - t);
        const float v1 = fminf(t - e.z, e.w - t);   // sentinel if p+1 == n_mine
        m2 = fmaxf(m2, fminf(m1, v0));   // uses OLD m1
        m1 = fmaxf(m1, v0);
        m2 = fmaxf(m2, fminf(m1, v1));
        m1 = fmaxf(m1, v1);
    }

    // ---- write out: per (b,c) layout is [D, K, T] = 128 floats ----
    float* o = out + (long)wid * 128;
    o[d_lane * 64 + t_idx] = m1;        // k = 0 (max)
    o[d_lane * 64 + 32 + t_idx] = m2;   // k = 1 (second max)
}

extern "C" void kernel_launch(void* const* d_in, const int* in_sizes, int n_in,
                              void* d_out, int out_size, void* d_ws, size_t ws_size,
                              hipStream_t stream) {
    const float* x = (const float*)d_in[0];
    const int* birth_idx = (const int*)d_in[1];
    const int* death_idx = (const int*)d_in[2];
    const int* pair_dim = (const int*)d_in[3];
    float* out = (float*)d_out;

    // 8192 (b,c) slices, one wave each, 4 waves per 256-thread block.
    dim3 grid(2048), block(256);
    hipLaunchKernelGGL(pl_topk_kernel, grid, block, 0, stream,
                       x, birth_idx, death_idx, pair_dim, out);
}

// Round 7
// 27.735 us; speedup vs baseline: 1.0220x; 1.0220x over previous
//
#include <hip/hip_runtime.h>

// CubPL2d: persistence landscape top-2 over pairs.
// x: [B=128, C=64, H=64, W=64] f32; birth/death/pair_dim: [B, C, P=128] i32.
// out: [B, C, D=2, K=2, T=32] f32.
//
// R6 = R5 with the staging bug fixed: slice = 4096 floats = 1024 float4,
// so each of the 256 threads must stage FOUR float4s (R5 staged one ->
// 3/4 of the LDS slice was garbage; absmax 3.06).
//
// Streaming formulation at full occupancy: one 256-thread block per slice,
// 16 KB slice + 2 KB tables = 18 KB LDS -> 8 blocks/CU = 32 waves/CU.
//   phase 1: stage slice (4 coalesced float4/thread) + idx loads (threads
//            0..127 own pair p = tid). __syncthreads.
//   phase 2: threads 0..127 gather (birth, death) from LDS, write masked
//            tables tab[d][p]; dim-fold sentinel (BIG,-BIG) in the other dim
//            (-> v ~ -1e30, no-op in the 0-init top-2). __syncthreads.
//   phase 3: slot s = tid>>2 (d = s>>5, t = s&31); quarter q = tid&3 scans
//            entries 4i+q (i<32); top-2 partials merged with 2 __shfl_xor
//            rounds (the 4 threads of a slot are consecutive -> same wave).

constexpr int P = 128;
constexpr float T_MIN = 0.03f;
constexpr float T_MAX = 0.34f;
constexpr float BIG = 1e30f;

__global__ __launch_bounds__(256) void pl_topk_kernel(
    const float* __restrict__ x,
    const int* __restrict__ birth_idx,
    const int* __restrict__ death_idx,
    const int* __restrict__ pair_dim,
    float* __restrict__ out)
{
    __shared__ float sl[4096];        // 16 KB x-slice
    __shared__ float2 tab[2][P];      // 2 KB dim-masked (birth, death) tables

    const int tid = threadIdx.x;
    const int wid = blockIdx.x;       // b*C + c, 0..8191

    // ---- phase 1: issue coalesced slice stream (4 float4/thread) ----
    const float4* xs = reinterpret_cast<const float4*>(x + (long)wid * 4096);
    float4 v4[4];
    #pragma unroll
    for (int c = 0; c < 4; ++c) v4[c] = xs[c * 256 + tid];

    int bi = 0, di = 0, dmv = 0;
    if (tid < P) {                    // thread tid owns pair tid
        const long pb = (long)wid * P;
        bi = birth_idx[pb + tid];
        di = death_idx[pb + tid];
        dmv = pair_dim[pb + tid];
    }

    #pragma unroll
    for (int c = 0; c < 4; ++c)
        *reinterpret_cast<float4*>(&sl[(c * 256 + tid) * 4]) = v4[c];
    __syncthreads();

    // ---- phase 2: LDS gather + masked table build ----
    if (tid < P) {
        const float xb = sl[bi];
        const float xd = sl[di];
        tab[dmv][tid] = make_float2(xb, xd);
        tab[1 - dmv][tid] = make_float2(BIG, -BIG);   // dim-fold sentinel
    }
    __syncthreads();

    // ---- phase 3: quarter-split top-2 scan + shuffle merge ----
    const int q = tid & 3;            // quarter of the pair list
    const int s = tid >> 2;           // output slot 0..63
    const int d = s >> 5;             // homology dim
    const int ti = s & 31;            // time step
    const float t = T_MIN + (T_MAX - T_MIN) * (float)ti * (1.0f / 31.0f);

    float m1 = 0.0f, m2 = 0.0f;
    #pragma unroll 8
    for (int i = 0; i < 32; ++i) {
        const float2 e = tab[d][4 * i + q];
        const float v = fminf(t - e.x, e.y - t);
        m2 = fmaxf(m2, fminf(m1, v));   // uses OLD m1
        m1 = fmaxf(m1, v);
    }
    // merge the 4 quarter-partials: top2(unionA ∪ unionB) per round
    {
        const float o1 = __shfl_xor(m1, 1, 64);
        const float o2 = __shfl_xor(m2, 1, 64);
        m2 = fmaxf(fmaxf(m2, o2), fminf(m1, o1));
        m1 = fmaxf(m1, o1);
    }
    {
        const float o1 = __shfl_xor(m1, 2, 64);
        const float o2 = __shfl_xor(m2, 2, 64);
        m2 = fmaxf(fmaxf(m2, o2), fminf(m1, o1));
        m1 = fmaxf(m1, o1);
    }

    // ---- write out: per (b,c) layout is [D, K, T] = 128 floats ----
    if (q == 0) {
        float* o = out + (long)wid * 128;
        o[d * 64 + ti] = m1;          // k = 0 (max)
        o[d * 64 + 32 + ti] = m2;     // k = 1 (second max)
    }
}

extern "C" void kernel_launch(void* const* d_in, const int* in_sizes, int n_in,
                              void* d_out, int out_size, void* d_ws, size_t ws_size,
                              hipStream_t stream) {
    const float* x = (const float*)d_in[0];
    const int* birth_idx = (const int*)d_in[1];
    const int* death_idx = (const int*)d_in[2];
    const int* pair_dim = (const int*)d_in[3];
    float* out = (float*)d_out;

    // one 256-thread block per (b,c) slice
    dim3 grid(8192), block(256);
    hipLaunchKernelGGL(pl_topk_kernel, grid, block, 0, stream,
                       x, birth_idx, death_idx, pair_dim, out);
}

// Round 8
// 25.950 us; speedup vs baseline: 1.0923x; 1.0688x over previous
//
#include <hip/hip_runtime.h>

// CubPL2d: persistence landscape top-2 over pairs.
// x: [B=128, C=64, H=64, W=64] f32; birth/death/pair_dim: [B, C, P=128] i32.
// out: [B, C, D=2, K=2, T=32] f32.
//
// R7 = R2 reverted (best of the 4-quadrant formulation matrix, 26.3 us):
//   gather@32waves/CU 26.3 | gather+2slice 27.6 | stream@8w 28.3 | stream@32w 27.7
// The kernel is memory-bound at ~133 MB of HBM traffic (116 MB touched
// x-lines — 256 random draws cover ~87% of each slice's 128B lines, so the
// gather is near-minimal — + 12.6 MB idx + 4.2 MB out) at the ~5 TB/s
// effective rate this random-gather pattern achieves (fills: 7 TB/s).
// Streaming the slices raises BW to ~5.5 TB/s but costs +13% traffic: a wash.
//
// Structure: one wave64 per (b,c). Lane l owns output slot (d=l>>5, t=l&31).
//  - COMPACTED per-dim LDS tables: pairs of dim d written contiguously at
//    position = ballot-popcount prefix (top-2 is order-independent). Scan
//    length n_d (~64) instead of 128; sentinel absorbs odd-tail b128 read.
//  - No __syncthreads: tables are wave-private; wave-local s_waitcnt
//    lgkmcnt(0) orders ds_write -> ds_read.
//  - idx loads as int2 (lane owns pairs 2l, 2l+1).

constexpr int P = 128;
constexpr float T_MIN = 0.03f;
constexpr float T_MAX = 0.34f;
constexpr float BIG = 1e30f;

__global__ __launch_bounds__(256) void pl_topk_kernel(
    const float* __restrict__ x,
    const int* __restrict__ birth_idx,
    const int* __restrict__ death_idx,
    const int* __restrict__ pair_dim,
    float* __restrict__ out)
{
    // [wave][dim][entry] -> (birth, death); 130 entries: up to 128 + sentinel,
    // and 16B alignment of each dim table (130*8B = 1040 = 65*16). ~8.3 KB/blk.
    __shared__ float2 tab[4][2][130];

    const int lane = threadIdx.x & 63;
    const int w = threadIdx.x >> 6;
    const int wid = blockIdx.x * 4 + w;   // wid = b*C + c, 0..8191

    const int d_lane = lane >> 5;    // homology dim this lane accumulates
    const int t_idx = lane & 31;     // time step this lane accumulates
    const float t = T_MIN + (T_MAX - T_MIN) * (float)t_idx * (1.0f / 31.0f);

    // ---- load this wave's 128 pairs (2 consecutive per lane), gather x ----
    const long pbase = (long)wid * P;
    const int2 bi = *reinterpret_cast<const int2*>(&birth_idx[pbase + 2 * lane]);
    const int2 di = *reinterpret_cast<const int2*>(&death_idx[pbase + 2 * lane]);
    const int2 dm = *reinterpret_cast<const int2*>(&pair_dim[pbase + 2 * lane]);

    const long xbase = (long)wid * 4096;  // H*W
    const float xb0 = x[xbase + bi.x];
    const float xb1 = x[xbase + bi.y];
    const float xd0 = x[xbase + di.x];
    const float xd1 = x[xbase + di.y];

    // ---- compaction positions via ballot popcount prefix ----
    const unsigned long long below = (lane == 63) ? ~0ull >> 1
                                                  : (1ull << lane) - 1ull;
    const unsigned long long a_d1 = __ballot(dm.x == 1);   // elem A dims
    const unsigned long long b_d1 = __ballot(dm.y == 1);   // elem B dims
    const unsigned long long a_d0 = ~a_d1;
    const unsigned long long b_d0 = ~b_d1;

    const int nA0 = __popcll(a_d0);                 // dim-0 count among A elems
    const int nA1 = 64 - nA0;
    const int n0 = nA0 + __popcll(b_d0);            // total dim-0 pairs
    const int n1 = P - n0;

    const unsigned long long myA = dm.x ? a_d1 : a_d0;
    const int posA = __popcll(myA & below);
    const unsigned long long myB = dm.y ? b_d1 : b_d0;
    const int posB = (dm.y ? nA1 : nA0) + __popcll(myB & below);

    tab[w][dm.x][posA] = make_float2(xb0, xd0);
    tab[w][dm.y][posB] = make_float2(xb1, xd1);
    if (lane == 0) tab[w][0][n0] = make_float2(BIG, -BIG);  // odd-tail sentinel
    if (lane == 1) tab[w][1][n1] = make_float2(BIG, -BIG);

    // wave-local ordering only: this wave's ds_writes before its ds_reads
    asm volatile("s_waitcnt lgkmcnt(0)" ::: "memory");

    // ---- top-2 scan over my dim's compacted list ----
    const int n_mine = d_lane ? n1 : n0;
    float m1 = 0.0f, m2 = 0.0f;
    const float2* tp = &tab[w][d_lane][0];
    #pragma unroll 2
    for (int p = 0; p < n_mine; p += 2) {
        const float4 e = *reinterpret_cast<const float4*>(&tp[p]);
        const float v0 = fminf(t - e.x, e.y - t);
        const float v1 = fminf(t - e.z, e.w - t);   // sentinel if p+1 == n_mine
        m2 = fmaxf(m2, fminf(m1, v0));   // uses OLD m1
        m1 = fmaxf(m1, v0);
        m2 = fmaxf(m2, fminf(m1, v1));
        m1 = fmaxf(m1, v1);
    }

    // ---- write out: per (b,c) layout is [D, K, T] = 128 floats ----
    float* o = out + (long)wid * 128;
    o[d_lane * 64 + t_idx] = m1;        // k = 0 (max)
    o[d_lane * 64 + 32 + t_idx] = m2;   // k = 1 (second max)
}

extern "C" void kernel_launch(void* const* d_in, const int* in_sizes, int n_in,
                              void* d_out, int out_size, void* d_ws, size_t ws_size,
                              hipStream_t stream) {
    const float* x = (const float*)d_in[0];
    const int* birth_idx = (const int*)d_in[1];
    const int* death_idx = (const int*)d_in[2];
    const int* pair_dim = (const int*)d_in[3];
    float* out = (float*)d_out;

    // 8192 (b,c) slices, one wave each, 4 waves per 256-thread block.
    dim3 grid(2048), block(256);
    hipLaunchKernelGGL(pl_topk_kernel, grid, block, 0, stream,
                       x, birth_idx, death_idx, pair_dim, out);
}